// Round 16
// baseline (229.013 us; speedup 1.0000x reference)
//
#include <hip/hip_runtime.h>
#include <math.h>

#define NB 16
#define CIN 128
#define COUT 128
#define SDIM 512
#define HH 128
#define WW 128

typedef __bf16 bf16x8 __attribute__((ext_vector_type(8)));
typedef float f32x16 __attribute__((ext_vector_type(16)));

static constexpr size_t WA_OFF = 8192;                          // after s (2048 f32)
static constexpr size_t WA_ELEMS = (size_t)NB * 9 * COUT * CIN; // 2,359,296 bf16
static constexpr size_t XT_OFF = WA_OFF + WA_ELEMS * 2;
static constexpr size_t XT_ELEMS = (size_t)NB * 130 * 130 * CIN;
static constexpr size_t WS_NEEDED = XT_OFF + XT_ELEMS * 2;

__device__ __forceinline__ unsigned short f32_bf16(float f) {
  unsigned int x = __float_as_uint(f);
  x += 0x7fffu + ((x >> 16) & 1u);
  return (unsigned short)(x >> 16);
}

__device__ __forceinline__ void gl_lds16(const void* g, void* l) {
  __builtin_amdgcn_global_load_lds((const __attribute__((address_space(1))) void*)g,
                                   (__attribute__((address_space(3))) void*)l, 16, 0, 0);
}

// ---------------- K0: s[b][cin] = style[b] . mod_w[cin] ----------------
__global__ void k_style(const float* __restrict__ style, const float* __restrict__ mod_w,
                        float* __restrict__ s) {
  int b = blockIdx.x, ci = threadIdx.x;
  const float4* st = (const float4*)(style + (size_t)b * SDIM);
  const float4* mw = (const float4*)(mod_w + (size_t)ci * SDIM);
  float acc = 0.f;
  for (int i = 0; i < SDIM / 4; ++i) {
    float4 a = st[i], m = mw[i];
    acc += a.x * m.x + a.y * m.y + a.z * m.z + a.w * m.w;
  }
  s[b * CIN + ci] = acc;
}

// ---------------- K1: demod + wA[b][tap][cout][cin] (bf16) ----------------
__global__ void k_wprep(const float* __restrict__ weight, const float* __restrict__ s,
                        unsigned short* __restrict__ wA) {
  int co = blockIdx.x, b = blockIdx.y, ci = threadIdx.x;
  const float scale = 0.029462782549439483f; // 1/sqrt(128*9)
  float sv = s[b * CIN + ci];
  const float* wp = weight + ((size_t)co * CIN + ci) * 9;
  float u[9], ss = 0.f;
#pragma unroll
  for (int t = 0; t < 9; ++t) { u[t] = scale * wp[t] * sv; ss += u[t] * u[t]; }
#pragma unroll
  for (int off = 32; off; off >>= 1) ss += __shfl_down(ss, off, 64);
  __shared__ float red[2];
  if ((threadIdx.x & 63) == 0) red[threadIdx.x >> 6] = ss;
  __syncthreads();
  float demod = rsqrtf(red[0] + red[1] + 1e-8f);
#pragma unroll
  for (int t = 0; t < 9; ++t)
    wA[((size_t)(b * 9 + t) * COUT + co) * CIN + ci] = f32_bf16(u[t] * demod);
}

// ---------------- K2: xt[b][hb][wb][cin] transpose, halo written in-kernel ----
__global__ void k_xt(const float* __restrict__ x, unsigned short* __restrict__ xt) {
  int hb = blockIdx.x, b = blockIdx.y;
  int t = threadIdx.x;
  unsigned short* orow = xt + ((size_t)b * 130 + hb) * 130 * CIN;
  if (hb == 0 || hb == 129) {
    uint4 z = {0u, 0u, 0u, 0u};
    for (int u = t; u < 2080; u += 256) ((uint4*)orow)[u] = z;
    return;
  }
  __shared__ unsigned short lds[128][132]; // [w][c]
  int h = hb - 1;
  const float* xrow = x + (size_t)b * CIN * HH * WW + (size_t)h * WW;
  for (int i = 0; i < 32; ++i) {
    int flat = i * 256 + t;
    int w = flat & 127, cp = flat >> 7;
    float a0 = xrow[(size_t)(2 * cp) * HH * WW + w];
    float a1 = xrow[(size_t)(2 * cp + 1) * HH * WW + w];
    unsigned int pk = (unsigned int)f32_bf16(a0) | ((unsigned int)f32_bf16(a1) << 16);
    *(unsigned int*)&lds[w][2 * cp] = pk;
  }
  __syncthreads();
  if (t < 32) {
    int side = t >> 4, g = t & 15;
    uint4 z = {0u, 0u, 0u, 0u};
    ((uint4*)(orow + (side ? (size_t)129 * CIN : 0)))[g] = z;
  }
  for (int i = 0; i < 8; ++i) {
    int u = i * 256 + t;
    int w = u >> 4, cg = u & 15;
    uint2 v0 = *(const uint2*)&lds[w][cg * 8];
    uint2 v1 = *(const uint2*)&lds[w][cg * 8 + 4];
    uint4 v = {v0.x, v0.y, v1.x, v1.y};
    *(uint4*)(orow + (size_t)(1 + w) * CIN + cg * 8) = v;
  }
}

// ---------------- K3: conv, SINGLE-STAGE read-only LDS, ONE barrier ----------------
// Stage the FULL x window (10 rows x 34 cols x 128 cin = 87KB bf16) into LDS
// once, __syncthreads once, then every wave free-runs 4 cin-chunks x 9 taps
// with only register dependencies: no LDS rewrites, no further barriers, no
// vmcnt drains. 88KB/block -> 1 block/CU = 8 waves/CU (proven-clean memory
// envelope; 256 resident blocks span 4 batches).
// 512 thr = 8 waves (wm: cout half, wn: hh pair); block tile = 128 cout x
// 8 hh x 32 ww; wave = 64 cout x (2 hh x 32 ww) via 32x32x16 MFMA, acc[2][2].
// LDS [row 0..9][g 0..15][col 0..33] 16B units: B-read lane stride 16B,
// conflict-free (r11+); source-permuted staging, linear dest (rule #21).
// Stores: each instruction writes 2 FULL 128B lines (r13-validated C/D map).
__launch_bounds__(512, 2)
__global__ void k_conv(const unsigned short* __restrict__ xt,
                       const unsigned short* __restrict__ wA,
                       const float* __restrict__ noise,
                       const float* __restrict__ nw,
                       float* __restrict__ out) {
  __shared__ uint4 ldsx[5504]; // 10*16*34 = 5440 used -> 88,064 B
  int b = blockIdx.y;
  int tile = blockIdx.x;               // 16 hbands x 4 wbands
  int th = (tile >> 2) * 8, tw = (tile & 3) * 32;
  int t = threadIdx.x;
  int lane = t & 63, wv = t >> 6;
  int wm = wv >> 2, wn = wv & 3;       // wm: cout 64-half, wn: hh pair
  int l31 = lane & 31, hi = lane >> 5; // l31: A-row / B-col(ww); hi: k-group

  f32x16 acc[2][2]; // [mt][nt]
#pragma unroll
  for (int mt = 0; mt < 2; ++mt)
#pragma unroll
    for (int nt = 0; nt < 2; ++nt)
#pragma unroll
      for (int r = 0; r < 16; ++r) acc[mt][nt][r] = 0.f;

  const unsigned short* xtile = xt + ((size_t)b * 130 + th) * 130 * CIN + (size_t)tw * CIN;
  const unsigned short* wbase = wA + (size_t)b * 9 * COUT * CIN
                                + (size_t)(wm * 64 + l31) * CIN + hi * 8;

  // ---- stage full x window once: unit u = (row*16+g)*34 + col ----
#pragma unroll
  for (int i = 0; i < 11; ++i) {
    int u = i * 512 + t;
    if (u < 5440) {
      int row = u / 544, rem = u - row * 544;
      int g = rem / 34, col = rem - g * 34;
      gl_lds16(xtile + ((size_t)row * 130 + col) * CIN + g * 8,
               &ldsx[i * 512 + wv * 64]);
    }
  }
  __syncthreads(); // the ONLY barrier

  const bf16x8* myl = (const bf16x8*)&ldsx[0];

  for (int q = 0; q < 4; ++q) {
    const unsigned short* wq = wbase + (size_t)q * 32;

    bf16x8 afA[4], afB[4]; // [mt*2+ks], 1-tap-ahead rotation
#pragma unroll
    for (int mt = 0; mt < 2; ++mt)
#pragma unroll
      for (int ks = 0; ks < 2; ++ks)
        afA[mt * 2 + ks] = *(const bf16x8*)(wq + (size_t)mt * 32 * CIN + ks * 16);

    auto TAPBODY = [&](int tap, bf16x8 (&cur)[4], bf16x8 (&nxt)[4]) {
      if (tap < 8) {
        const unsigned short* wt = wq + (size_t)(tap + 1) * COUT * CIN;
#pragma unroll
        for (int mt = 0; mt < 2; ++mt)
#pragma unroll
          for (int ks = 0; ks < 2; ++ks)
            nxt[mt * 2 + ks] = *(const bf16x8*)(wt + (size_t)mt * 32 * CIN + ks * 16);
      }
      int ky = tap / 3, kx = tap - 3 * (tap / 3);
#pragma unroll
      for (int nt = 0; nt < 2; ++nt) {
        int row0 = wn * 2 + nt + ky;       // 0..9
        int c0 = l31 + kx;                 // 0..33
#pragma unroll
        for (int ks = 0; ks < 2; ++ks) {
          bf16x8 bv = myl[(size_t)(row0 * 16 + q * 4 + ks * 2 + hi) * 34 + c0];
          acc[0][nt] = __builtin_amdgcn_mfma_f32_32x32x16_bf16(cur[ks],     bv, acc[0][nt], 0, 0, 0);
          acc[1][nt] = __builtin_amdgcn_mfma_f32_32x32x16_bf16(cur[2 + ks], bv, acc[1][nt], 0, 0, 0);
        }
      }
    };

    TAPBODY(0, afA, afB);
    TAPBODY(1, afB, afA);
    TAPBODY(2, afA, afB);
    TAPBODY(3, afB, afA);
    TAPBODY(4, afA, afB);
    TAPBODY(5, afB, afA);
    TAPBODY(6, afA, afB);
    TAPBODY(7, afB, afA);
    TAPBODY(8, afA, afB);
  }

  // ---- epilogue: each store instruction writes 2 FULL 128B lines ----
#pragma unroll
  for (int nt = 0; nt < 2; ++nt) {
    int hh = th + wn * 2 + nt;
    float nv = noise[((size_t)b * HH + hh) * WW + tw + l31];
#pragma unroll
    for (int mt = 0; mt < 2; ++mt) {
#pragma unroll
      for (int r = 0; r < 16; ++r) {
        int cout = wm * 64 + mt * 32 + (r & 3) + 8 * (r >> 2) + 4 * hi;
        out[(((size_t)b * COUT + cout) * HH + hh) * WW + tw + l31] =
            acc[mt][nt][r] + nw[cout] * nv;
      }
    }
  }
}

extern "C" void kernel_launch(void* const* d_in, const int* in_sizes, int n_in,
                              void* d_out, int out_size, void* d_ws, size_t ws_size,
                              hipStream_t stream) {
  const float* x      = (const float*)d_in[0];
  const float* style  = (const float*)d_in[1];
  const float* noise  = (const float*)d_in[2];
  const float* weight = (const float*)d_in[3];
  const float* mod_w  = (const float*)d_in[4];
  const float* nw     = (const float*)d_in[5];
  float* out = (float*)d_out;
  char* ws = (char*)d_ws;
  if (ws_size < WS_NEEDED) return;

  float* s = (float*)ws;
  unsigned short* wA = (unsigned short*)(ws + WA_OFF);
  unsigned short* xt = (unsigned short*)(ws + XT_OFF);

  k_style<<<dim3(NB), dim3(CIN), 0, stream>>>(style, mod_w, s);
  k_wprep<<<dim3(COUT, NB), dim3(CIN), 0, stream>>>(weight, s, wA);
  k_xt<<<dim3(130, NB), dim3(256), 0, stream>>>(x, xt);
  k_conv<<<dim3(64, NB), dim3(512), 0, stream>>>(xt, wA, noise, nw, out);
}